// Round 7
// baseline (2339.134 us; speedup 1.0000x reference)
//
#include <hip/hip_runtime.h>

// LTC fused scan kernel for MI355X.
// B=512 batch rows, one 256-thread workgroup (4 waves) each.
// lane = unit index j (U=64). Waves split the i-reduction:
//   sensory: wave w owns i in [32w, 32w+32)   (I=128)
//   recurrent: wave w owns i in [16w, 16w+16) (U=64)
// All per-synapse params live in registers (pre-transformed once):
//   sigmoid(sigma*(v-mu)) = 1/(1+2^(a*v + c)), a = -log2e*sigma,
//   c = log2e*sigma*mu.  Input affine folded into sensory params.
// erev is exactly +-1, so swe = softplus(w)*erev carries the denominator
// weight as |swe| (abs() is a free VOP3 input modifier).
// PAIRED-RCP (round 6, verified -7%): two sigmoid terms share one rcp:
//   w_a/q_a + w_b/q_b = (w_a*q_b + w_b*q_a) * rcp(q_a*q_b),  q = 1+e.
// Software-pipelined sensory phase (round 5): t+1 sensory terms computed
// in the post-barrier shadow of t's unfolds.
//
// Round 7 (bit-exact scheduling changes only):
// 1. LGKM-ONLY BARRIERS: __syncthreads() compiles to
//    s_waitcnt vmcnt(0) lgkmcnt(0) + s_barrier; the vmcnt(0) force-drains
//    the in-flight x[t+2] prefetch at unfold-0's barrier EVERY timestep,
//    exposing global-load latency. The exchange only needs LDS
//    visibility -> inline-asm "s_waitcnt lgkmcnt(0); s_barrier"
//    (memory clobber keeps LDS ops ordered; the compiler still inserts
//    its own vmcnt before xv_pp's consumption 4 barriers later).
// 2. s_setprio(1) during compute bursts, (0) at barriers: the two
//    independent blocks per CU are phase-shifted, so the scheduler can
//    prefer a mid-burst wave over one about to spin at s_barrier.

#define NB 512
#define NT 512
#define NI 128
#define NU 64
#define NO 15
#define L2E 1.44269504088896340736f

__device__ __forceinline__ float bcastf(float v, int lane) {
  return __int_as_float(__builtin_amdgcn_readlane(__float_as_int(v), lane));
}

__device__ __forceinline__ float wsum64(float x) {
#pragma unroll
  for (int m = 32; m >= 1; m >>= 1) x += __shfl_xor(x, m, 64);
  return x;
}

__device__ __forceinline__ float softplus_f(float x) {
  // matches jax.nn.softplus for our input range (x in [-0.2, 1])
  return log1pf(expf(x));
}

// Workgroup barrier with LDS-only visibility (no vmcnt drain).
__device__ __forceinline__ void barrier_lds() {
  asm volatile("s_waitcnt lgkmcnt(0)\n\ts_barrier" ::: "memory");
}

// Accumulate w0/(1+2^(a0*vb0+c0)) + w1/(1+2^(a1*vb1+c1)) into (num) and
// the |w|-weighted version into (den), sharing ONE rcp between the pair.
__device__ __forceinline__ void sigm_pair(
    float a0, float vb0, float c0, float w0,
    float a1, float vb1, float c1, float w1,
    float& num, float& den)
{
  const float e0 = __builtin_amdgcn_exp2f(fmaf(a0, vb0, c0));
  const float e1 = __builtin_amdgcn_exp2f(fmaf(a1, vb1, c1));
  const float q0 = 1.0f + e0;
  const float q1 = 1.0f + e1;
  const float r  = __builtin_amdgcn_rcpf(q0 * q1);
  const float np = fmaf(w0, q1, w1 * q0);
  const float dp = fmaf(fabsf(w0), q1, fabsf(w1) * q0);
  num = fmaf(np, r, num);
  den = fmaf(dp, r, den);
}

__global__ __launch_bounds__(256, 1) void ltc_fused(
    const float* __restrict__ x,
    const float* __restrict__ input_w, const float* __restrict__ input_b,
    const float* __restrict__ sensory_w, const float* __restrict__ sensory_mu,
    const float* __restrict__ sensory_sigma, const float* __restrict__ sensory_erev,
    const float* __restrict__ w_, const float* __restrict__ mu_,
    const float* __restrict__ sigma_, const float* __restrict__ erev_,
    const float* __restrict__ gleak, const float* __restrict__ vleak,
    const float* __restrict__ cm,
    const float* __restrict__ output_w, const float* __restrict__ output_b,
    const float* __restrict__ ln_w, const float* __restrict__ ln_b,
    const float* __restrict__ fc_w, const float* __restrict__ fc_b,
    float* __restrict__ out)
{
  const int b    = blockIdx.x;
  const int tid  = threadIdx.x;
  const int wv   = tid >> 6;     // wave 0..3
  const int lane = tid & 63;     // unit j

  __shared__ float2 xbuf[4][4][NU];   // [unfold][wave][lane] partial (num,den)

  // ---- load + transform sensory params: i = 32*wv + k, j = lane ----
  // input affine folded in: z = (a*iw)*x + (a*ib + c)
  float sa[32], sc[32], swe[32];
#pragma unroll
  for (int k = 0; k < 32; ++k) {
    const int i   = 32 * wv + k;
    const int idx = i * NU + lane;
    const float ss  = sensory_sigma[idx];
    const float sm  = sensory_mu[idx];
    const float sw  = softplus_f(sensory_w[idx]);
    const float se  = sensory_erev[idx];
    const float iwk = input_w[i];
    const float ibk = input_b[i];
    const float a = -L2E * ss;
    const float c =  L2E * ss * sm;
    sa[k]  = a * iwk;
    sc[k]  = fmaf(a, ibk, c);
    swe[k] = sw * se;                 // |swe| == softplus(w), since se = +-1
  }
  // ---- recurrent params: i = 16*wv + k, j = lane ----
  float ra[16], rc[16], rwe[16];
#pragma unroll
  for (int k = 0; k < 16; ++k) {
    const int idx = (16 * wv + k) * NU + lane;
    const float sg = sigma_[idx];
    const float m  = mu_[idx];
    const float ww = softplus_f(w_[idx]);
    const float ev = erev_[idx];
    ra[k]  = -L2E * sg;
    rc[k]  =  L2E * sg * m;
    rwe[k] = ww * ev;                 // |rwe| == softplus(w)
  }

  // ---- per-neuron constants (lane = j) ----
  const float glp   = softplus_f(gleak[lane]);
  const float cmt   = softplus_f(cm[lane]) * 4.0f;   // softplus(cm)/(1/UNFOLDS)
  const float glvl  = glp * vleak[lane];
  const float dbase = cmt + glp + 1e-8f;             // fold EPS in once

  // lane's sensory input index for the x-load (lanes 32..63 duplicate 0..31)
  const int ii = 32 * wv + (lane & 31);

  float v = 0.0f;
  const float* xp = x + (size_t)b * NT * NI + ii;

  // ---- prologue: sensory sums for t = 0 (16 pairs, 4 chains) ----
  float wns, wds;
  {
    const float xv0 = xp[0];
    float n0=0.f, n1=0.f, n2=0.f, n3=0.f;
    float d0=0.f, d1=0.f, d2=0.f, d3=0.f;
#pragma unroll
    for (int k = 0; k < 32; k += 8) {
      sigm_pair(sa[k+0], bcastf(xv0, k+0), sc[k+0], swe[k+0],
                sa[k+1], bcastf(xv0, k+1), sc[k+1], swe[k+1], n0, d0);
      sigm_pair(sa[k+2], bcastf(xv0, k+2), sc[k+2], swe[k+2],
                sa[k+3], bcastf(xv0, k+3), sc[k+3], swe[k+3], n1, d1);
      sigm_pair(sa[k+4], bcastf(xv0, k+4), sc[k+4], swe[k+4],
                sa[k+5], bcastf(xv0, k+5), sc[k+5], swe[k+5], n2, d2);
      sigm_pair(sa[k+6], bcastf(xv0, k+6), sc[k+6], swe[k+6],
                sa[k+7], bcastf(xv0, k+7), sc[k+7], swe[k+7], n3, d3);
    }
    wns = (n0 + n1) + (n2 + n3);
    wds = (d0 + d1) + (d2 + d3);
  }
  float xv_next = xp[NI];   // x[t=1]

  __builtin_amdgcn_s_setprio(1);
#pragma unroll 1
  for (int t = 0; t < NT; ++t) {
    const int tpp = (t + 2 < NT) ? (t + 2) : (NT - 1);
    const float xv_pp = xp[(size_t)tpp * NI];     // prefetch x[t+2]
    // t+1 sensory accumulators, filled chunk-wise inside the unfolds
    float nsn0=0.f, nsn1=0.f, dsn0=0.f, dsn1=0.f;

    // ---- 4 ODE unfolds, each hosting one 8-term sensory chunk of t+1 ----
#pragma unroll
    for (int u = 0; u < 4; ++u) {
      float rn0=0.f, rn1=0.f, rn2=0.f, rn3=0.f;
      float rd0=0.f, rd1=0.f, rd2=0.f, rd3=0.f;
      const int i0 = 16 * wv;
      // 8 recurrent pairs, 4 chains
#pragma unroll
      for (int k = 0; k < 16; k += 8) {
        sigm_pair(ra[k+0], bcastf(v, i0+k+0), rc[k+0], rwe[k+0],
                  ra[k+1], bcastf(v, i0+k+1), rc[k+1], rwe[k+1], rn0, rd0);
        sigm_pair(ra[k+2], bcastf(v, i0+k+2), rc[k+2], rwe[k+2],
                  ra[k+3], bcastf(v, i0+k+3), rc[k+3], rwe[k+3], rn1, rd1);
        sigm_pair(ra[k+4], bcastf(v, i0+k+4), rc[k+4], rwe[k+4],
                  ra[k+5], bcastf(v, i0+k+5), rc[k+5], rwe[k+5], rn2, rd2);
        sigm_pair(ra[k+6], bcastf(v, i0+k+6), rc[k+6], rwe[k+6],
                  ra[k+7], bcastf(v, i0+k+7), rc[k+7], rwe[k+7], rn3, rd3);
      }
      // fold my sensory partial into my exchanged partial
      const float np = ((rn0 + rn1) + (rn2 + rn3)) + wns;
      const float dp = ((rd0 + rd1) + (rd2 + rd3)) + wds;
      xbuf[u][wv][lane] = make_float2(np, dp);
      __builtin_amdgcn_s_setprio(0);
      barrier_lds();
      __builtin_amdgcn_s_setprio(1);
      const float2 p0 = xbuf[u][0][lane];
      const float2 p1 = xbuf[u][1][lane];
      const float2 p2 = xbuf[u][2][lane];
      const float2 p3 = xbuf[u][3][lane];
      // sensory chunk u for t+1 (4 pairs, independent of v) -- scheduled
      // into the ds_read latency + v-update chain shadow
      {
        const int kk = 8 * u;
        sigm_pair(sa[kk+0], bcastf(xv_next, kk+0), sc[kk+0], swe[kk+0],
                  sa[kk+1], bcastf(xv_next, kk+1), sc[kk+1], swe[kk+1], nsn0, dsn0);
        sigm_pair(sa[kk+2], bcastf(xv_next, kk+2), sc[kk+2], swe[kk+2],
                  sa[kk+3], bcastf(xv_next, kk+3), sc[kk+3], swe[kk+3], nsn1, dsn1);
        sigm_pair(sa[kk+4], bcastf(xv_next, kk+4), sc[kk+4], swe[kk+4],
                  sa[kk+5], bcastf(xv_next, kk+5), sc[kk+5], swe[kk+5], nsn0, dsn0);
        sigm_pair(sa[kk+6], bcastf(xv_next, kk+6), sc[kk+6], swe[kk+6],
                  sa[kk+7], bcastf(xv_next, kk+7), sc[kk+7], swe[kk+7], nsn1, dsn1);
      }
      const float num = fmaf(cmt, v, glvl) + ((p0.x + p1.x) + (p2.x + p3.x));
      const float den = dbase + ((p0.y + p1.y) + (p2.y + p3.y));
      v = num * __builtin_amdgcn_rcpf(den);
      // note: next write to xbuf[u] is 4 barriers away -> no WAR hazard
    }
    wns = nsn0 + nsn1;
    wds = dsn0 + dsn1;
    xv_next = xv_pp;
  }
  __builtin_amdgcn_s_setprio(0);

  // ---- head: affine out-map, LayerNorm(eps=1e-5), fc (O=15) ----
  if (wv == 0) {
    const float h    = fmaf(v, output_w[lane], output_b[lane]);
    const float mean = wsum64(h) * (1.0f / 64.0f);
    const float d    = h - mean;
    const float var  = wsum64(d * d) * (1.0f / 64.0f);
    const float hn   = d * rsqrtf(var + 1e-5f) * ln_w[lane] + ln_b[lane];
#pragma unroll
    for (int o = 0; o < NO; ++o) {
      const float p = wsum64(hn * fc_w[o * NU + lane]);
      if (lane == 0) out[b * NO + o] = p + fc_b[o];
    }
  }
}

extern "C" void kernel_launch(void* const* d_in, const int* in_sizes, int n_in,
                              void* d_out, int out_size, void* d_ws, size_t ws_size,
                              hipStream_t stream) {
  const float* x             = (const float*)d_in[0];
  const float* input_w       = (const float*)d_in[1];
  const float* input_b       = (const float*)d_in[2];
  const float* sensory_w     = (const float*)d_in[3];
  const float* sensory_mu    = (const float*)d_in[4];
  const float* sensory_sigma = (const float*)d_in[5];
  const float* sensory_erev  = (const float*)d_in[6];
  const float* w_            = (const float*)d_in[7];
  const float* mu_           = (const float*)d_in[8];
  const float* sigma_        = (const float*)d_in[9];
  const float* erev_         = (const float*)d_in[10];
  const float* gleak         = (const float*)d_in[11];
  const float* vleak         = (const float*)d_in[12];
  const float* cm            = (const float*)d_in[13];
  const float* output_w      = (const float*)d_in[14];
  const float* output_b      = (const float*)d_in[15];
  const float* ln_w          = (const float*)d_in[16];
  const float* ln_b          = (const float*)d_in[17];
  const float* fc_w          = (const float*)d_in[18];
  const float* fc_b          = (const float*)d_in[19];
  float* out = (float*)d_out;

  ltc_fused<<<dim3(NB), dim3(256), 0, stream>>>(
      x, input_w, input_b, sensory_w, sensory_mu, sensory_sigma, sensory_erev,
      w_, mu_, sigma_, erev_, gleak, vleak, cm, output_w, output_b,
      ln_w, ln_b, fc_w, fc_b, out);
}

// Round 8
// 1917.849 us; speedup vs baseline: 1.2197x; 1.2197x over previous
//
#include <hip/hip_runtime.h>

// LTC fused scan kernel for MI355X.
// B=512 batch rows, one 256-thread workgroup (4 waves) each.
// lane = unit index j (U=64). Waves split the i-reduction:
//   sensory: wave w owns i in [32w, 32w+32)   (I=128)
//   recurrent: wave w owns i in [16w, 16w+16) (U=64)
// All per-synapse params live in registers (pre-transformed once):
//   sigmoid(sigma*(v-mu)) = 1/(1+2^(a*v + c)), a = -log2e*sigma,
//   c = log2e*sigma*mu.  Input affine folded into sensory params.
// erev is exactly +-1, so swe = softplus(w)*erev carries the denominator
// weight as |swe| (abs() is a free VOP3 input modifier).
// PAIRED-RCP (round 6, verified -7%): two sigmoid terms share one rcp:
//   w_a/q_a + w_b/q_b = (w_a*q_b + w_b*q_a) * rcp(q_a*q_b),  q = 1+e.
// Software-pipelined sensory phase (round 5): t+1 sensory terms computed
// in the post-barrier shadow of t's unfolds.
//
// Round 8: REVERT of round 7's scheduling overrides. The inline-asm
// lgkm-only barrier ("memory" clobber) walled off the compiler's
// cross-barrier scheduling -- exactly the scheduling that places the
// sensory chunks into the barrier shadows -- and regressed 21%
// (VALUBusy 85->70, dyn occupancy 18.3->11.9, VGPR 128->132).
// __syncthreads() + compiler-chosen schedule is the verified optimum.
// Session ledger: 4-wave geometry optimal (r1/r4), no spill (r3/r6),
// paired-rcp (r6), sensory pipelining (r5), scheduling overrides
// regress (r7). Kernel is transcendental-pipe bound at ~85% issue
// occupancy; exp2 count (one per synapse) is algorithmically
// irreducible.

#define NB 512
#define NT 512
#define NI 128
#define NU 64
#define NO 15
#define L2E 1.44269504088896340736f

__device__ __forceinline__ float bcastf(float v, int lane) {
  return __int_as_float(__builtin_amdgcn_readlane(__float_as_int(v), lane));
}

__device__ __forceinline__ float wsum64(float x) {
#pragma unroll
  for (int m = 32; m >= 1; m >>= 1) x += __shfl_xor(x, m, 64);
  return x;
}

__device__ __forceinline__ float softplus_f(float x) {
  // matches jax.nn.softplus for our input range (x in [-0.2, 1])
  return log1pf(expf(x));
}

// Accumulate w0/(1+2^(a0*vb0+c0)) + w1/(1+2^(a1*vb1+c1)) into (num) and
// the |w|-weighted version into (den), sharing ONE rcp between the pair.
__device__ __forceinline__ void sigm_pair(
    float a0, float vb0, float c0, float w0,
    float a1, float vb1, float c1, float w1,
    float& num, float& den)
{
  const float e0 = __builtin_amdgcn_exp2f(fmaf(a0, vb0, c0));
  const float e1 = __builtin_amdgcn_exp2f(fmaf(a1, vb1, c1));
  const float q0 = 1.0f + e0;
  const float q1 = 1.0f + e1;
  const float r  = __builtin_amdgcn_rcpf(q0 * q1);
  const float np = fmaf(w0, q1, w1 * q0);
  const float dp = fmaf(fabsf(w0), q1, fabsf(w1) * q0);
  num = fmaf(np, r, num);
  den = fmaf(dp, r, den);
}

__global__ __launch_bounds__(256, 1) void ltc_fused(
    const float* __restrict__ x,
    const float* __restrict__ input_w, const float* __restrict__ input_b,
    const float* __restrict__ sensory_w, const float* __restrict__ sensory_mu,
    const float* __restrict__ sensory_sigma, const float* __restrict__ sensory_erev,
    const float* __restrict__ w_, const float* __restrict__ mu_,
    const float* __restrict__ sigma_, const float* __restrict__ erev_,
    const float* __restrict__ gleak, const float* __restrict__ vleak,
    const float* __restrict__ cm,
    const float* __restrict__ output_w, const float* __restrict__ output_b,
    const float* __restrict__ ln_w, const float* __restrict__ ln_b,
    const float* __restrict__ fc_w, const float* __restrict__ fc_b,
    float* __restrict__ out)
{
  const int b    = blockIdx.x;
  const int tid  = threadIdx.x;
  const int wv   = tid >> 6;     // wave 0..3
  const int lane = tid & 63;     // unit j

  __shared__ float2 xbuf[4][4][NU];   // [unfold][wave][lane] partial (num,den)

  // ---- load + transform sensory params: i = 32*wv + k, j = lane ----
  // input affine folded in: z = (a*iw)*x + (a*ib + c)
  float sa[32], sc[32], swe[32];
#pragma unroll
  for (int k = 0; k < 32; ++k) {
    const int i   = 32 * wv + k;
    const int idx = i * NU + lane;
    const float ss  = sensory_sigma[idx];
    const float sm  = sensory_mu[idx];
    const float sw  = softplus_f(sensory_w[idx]);
    const float se  = sensory_erev[idx];
    const float iwk = input_w[i];
    const float ibk = input_b[i];
    const float a = -L2E * ss;
    const float c =  L2E * ss * sm;
    sa[k]  = a * iwk;
    sc[k]  = fmaf(a, ibk, c);
    swe[k] = sw * se;                 // |swe| == softplus(w), since se = +-1
  }
  // ---- recurrent params: i = 16*wv + k, j = lane ----
  float ra[16], rc[16], rwe[16];
#pragma unroll
  for (int k = 0; k < 16; ++k) {
    const int idx = (16 * wv + k) * NU + lane;
    const float sg = sigma_[idx];
    const float m  = mu_[idx];
    const float ww = softplus_f(w_[idx]);
    const float ev = erev_[idx];
    ra[k]  = -L2E * sg;
    rc[k]  =  L2E * sg * m;
    rwe[k] = ww * ev;                 // |rwe| == softplus(w)
  }

  // ---- per-neuron constants (lane = j) ----
  const float glp   = softplus_f(gleak[lane]);
  const float cmt   = softplus_f(cm[lane]) * 4.0f;   // softplus(cm)/(1/UNFOLDS)
  const float glvl  = glp * vleak[lane];
  const float dbase = cmt + glp + 1e-8f;             // fold EPS in once

  // lane's sensory input index for the x-load (lanes 32..63 duplicate 0..31)
  const int ii = 32 * wv + (lane & 31);

  float v = 0.0f;
  const float* xp = x + (size_t)b * NT * NI + ii;

  // ---- prologue: sensory sums for t = 0 (16 pairs, 4 chains) ----
  float wns, wds;
  {
    const float xv0 = xp[0];
    float n0=0.f, n1=0.f, n2=0.f, n3=0.f;
    float d0=0.f, d1=0.f, d2=0.f, d3=0.f;
#pragma unroll
    for (int k = 0; k < 32; k += 8) {
      sigm_pair(sa[k+0], bcastf(xv0, k+0), sc[k+0], swe[k+0],
                sa[k+1], bcastf(xv0, k+1), sc[k+1], swe[k+1], n0, d0);
      sigm_pair(sa[k+2], bcastf(xv0, k+2), sc[k+2], swe[k+2],
                sa[k+3], bcastf(xv0, k+3), sc[k+3], swe[k+3], n1, d1);
      sigm_pair(sa[k+4], bcastf(xv0, k+4), sc[k+4], swe[k+4],
                sa[k+5], bcastf(xv0, k+5), sc[k+5], swe[k+5], n2, d2);
      sigm_pair(sa[k+6], bcastf(xv0, k+6), sc[k+6], swe[k+6],
                sa[k+7], bcastf(xv0, k+7), sc[k+7], swe[k+7], n3, d3);
    }
    wns = (n0 + n1) + (n2 + n3);
    wds = (d0 + d1) + (d2 + d3);
  }
  float xv_next = xp[NI];   // x[t=1]

#pragma unroll 1
  for (int t = 0; t < NT; ++t) {
    const int tpp = (t + 2 < NT) ? (t + 2) : (NT - 1);
    const float xv_pp = xp[(size_t)tpp * NI];     // prefetch x[t+2]
    // t+1 sensory accumulators, filled chunk-wise inside the unfolds
    float nsn0=0.f, nsn1=0.f, dsn0=0.f, dsn1=0.f;

    // ---- 4 ODE unfolds, each hosting one 8-term sensory chunk of t+1 ----
#pragma unroll
    for (int u = 0; u < 4; ++u) {
      float rn0=0.f, rn1=0.f, rn2=0.f, rn3=0.f;
      float rd0=0.f, rd1=0.f, rd2=0.f, rd3=0.f;
      const int i0 = 16 * wv;
      // 8 recurrent pairs, 4 chains
#pragma unroll
      for (int k = 0; k < 16; k += 8) {
        sigm_pair(ra[k+0], bcastf(v, i0+k+0), rc[k+0], rwe[k+0],
                  ra[k+1], bcastf(v, i0+k+1), rc[k+1], rwe[k+1], rn0, rd0);
        sigm_pair(ra[k+2], bcastf(v, i0+k+2), rc[k+2], rwe[k+2],
                  ra[k+3], bcastf(v, i0+k+3), rc[k+3], rwe[k+3], rn1, rd1);
        sigm_pair(ra[k+4], bcastf(v, i0+k+4), rc[k+4], rwe[k+4],
                  ra[k+5], bcastf(v, i0+k+5), rc[k+5], rwe[k+5], rn2, rd2);
        sigm_pair(ra[k+6], bcastf(v, i0+k+6), rc[k+6], rwe[k+6],
                  ra[k+7], bcastf(v, i0+k+7), rc[k+7], rwe[k+7], rn3, rd3);
      }
      // fold my sensory partial into my exchanged partial
      const float np = ((rn0 + rn1) + (rn2 + rn3)) + wns;
      const float dp = ((rd0 + rd1) + (rd2 + rd3)) + wds;
      xbuf[u][wv][lane] = make_float2(np, dp);
      __syncthreads();
      const float2 p0 = xbuf[u][0][lane];
      const float2 p1 = xbuf[u][1][lane];
      const float2 p2 = xbuf[u][2][lane];
      const float2 p3 = xbuf[u][3][lane];
      // sensory chunk u for t+1 (4 pairs, independent of v) -- scheduled
      // into the ds_read latency + v-update chain shadow
      {
        const int kk = 8 * u;
        sigm_pair(sa[kk+0], bcastf(xv_next, kk+0), sc[kk+0], swe[kk+0],
                  sa[kk+1], bcastf(xv_next, kk+1), sc[kk+1], swe[kk+1], nsn0, dsn0);
        sigm_pair(sa[kk+2], bcastf(xv_next, kk+2), sc[kk+2], swe[kk+2],
                  sa[kk+3], bcastf(xv_next, kk+3), sc[kk+3], swe[kk+3], nsn1, dsn1);
        sigm_pair(sa[kk+4], bcastf(xv_next, kk+4), sc[kk+4], swe[kk+4],
                  sa[kk+5], bcastf(xv_next, kk+5), sc[kk+5], swe[kk+5], nsn0, dsn0);
        sigm_pair(sa[kk+6], bcastf(xv_next, kk+6), sc[kk+6], swe[kk+6],
                  sa[kk+7], bcastf(xv_next, kk+7), sc[kk+7], swe[kk+7], nsn1, dsn1);
      }
      const float num = fmaf(cmt, v, glvl) + ((p0.x + p1.x) + (p2.x + p3.x));
      const float den = dbase + ((p0.y + p1.y) + (p2.y + p3.y));
      v = num * __builtin_amdgcn_rcpf(den);
      // note: next write to xbuf[u] is 4 barriers away -> no WAR hazard
    }
    wns = nsn0 + nsn1;
    wds = dsn0 + dsn1;
    xv_next = xv_pp;
  }

  // ---- head: affine out-map, LayerNorm(eps=1e-5), fc (O=15) ----
  if (wv == 0) {
    const float h    = fmaf(v, output_w[lane], output_b[lane]);
    const float mean = wsum64(h) * (1.0f / 64.0f);
    const float d    = h - mean;
    const float var  = wsum64(d * d) * (1.0f / 64.0f);
    const float hn   = d * rsqrtf(var + 1e-5f) * ln_w[lane] + ln_b[lane];
#pragma unroll
    for (int o = 0; o < NO; ++o) {
      const float p = wsum64(hn * fc_w[o * NU + lane]);
      if (lane == 0) out[b * NO + o] = p + fc_b[o];
    }
  }
}

extern "C" void kernel_launch(void* const* d_in, const int* in_sizes, int n_in,
                              void* d_out, int out_size, void* d_ws, size_t ws_size,
                              hipStream_t stream) {
  const float* x             = (const float*)d_in[0];
  const float* input_w       = (const float*)d_in[1];
  const float* input_b       = (const float*)d_in[2];
  const float* sensory_w     = (const float*)d_in[3];
  const float* sensory_mu    = (const float*)d_in[4];
  const float* sensory_sigma = (const float*)d_in[5];
  const float* sensory_erev  = (const float*)d_in[6];
  const float* w_            = (const float*)d_in[7];
  const float* mu_           = (const float*)d_in[8];
  const float* sigma_        = (const float*)d_in[9];
  const float* erev_         = (const float*)d_in[10];
  const float* gleak         = (const float*)d_in[11];
  const float* vleak         = (const float*)d_in[12];
  const float* cm            = (const float*)d_in[13];
  const float* output_w      = (const float*)d_in[14];
  const float* output_b      = (const float*)d_in[15];
  const float* ln_w          = (const float*)d_in[16];
  const float* ln_b          = (const float*)d_in[17];
  const float* fc_w          = (const float*)d_in[18];
  const float* fc_b          = (const float*)d_in[19];
  float* out = (float*)d_out;

  ltc_fused<<<dim3(NB), dim3(256), 0, stream>>>(
      x, input_w, input_b, sensory_w, sensory_mu, sensory_sigma, sensory_erev,
      w_, mu_, sigma_, erev_, gleak, vleak, cm, output_w, output_b,
      ln_w, ln_b, fc_w, fc_b, out);
}